// Round 10
// baseline (150.629 us; speedup 1.0000x reference)
//
#include <hip/hip_runtime.h>
#include <stdint.h>

// out[n,o] = sum_{d,i} q[n,d] x[n,i] W1[d,i,o] + (q @ b1)[n,o]
// GEMM M=4096 N=256 K=16384 (k = d*256 + i), fp16 MFMA 32x32x16, fp32 accum.
//
// ROUND 10: first config combining (a) 4 waves/SIMD, (b) load:MFMA 1:4,
// (c) W traffic 256 MB. All prior rounds had at most 2 of the 3 (R8: 2
// waves/SIMD; R6: 4 waves but 1 GB + 1:1). Grid 512 = 32 mb x 8 nc x 2 ksi
// (ic-half), 512-thr blocks -> 2 blocks/CU. Block = 128 rows x 32 cols;
// wave owns 8 d's (full row-tile), ksi halves i. Per wave per ic: 4
// ds_read_b128 (x staged once in LDS, 8x cross-wave reuse) + 8 W loads
// (depth-4 reg ring) + 32 MFMA; 64 steps fully unrolled, NO barriers in the
// K-loop. Register budget audited for launch_bounds(512,4)=128: acc 64 +
// ring 16 + xf 16 + qv 16 + ~15 addr. d-rotation rot=mb&7 staggers same-
// slice blocks (q loaded rotated so hot loop stays static). Epilogue:
// two-phase LDS d-reduce (smem unioned with x-stage) -> 2 fp32 stripes +
// reduce2. Bias q@b1 folded into wave 7 of ksi==0 blocks.

typedef _Float16 f16;
typedef f16 f16x8 __attribute__((ext_vector_type(8)));
typedef float f32x16 __attribute__((ext_vector_type(16)));

#define QDIM 64

__device__ __forceinline__ void gl_lds16(const void* g, void* s) {
  __builtin_amdgcn_global_load_lds(
      (const __attribute__((address_space(1))) void*)(uintptr_t)g,
      (__attribute__((address_space(3))) void*)(uint32_t)(uintptr_t)s,
      16, 0, 0);
}

// one fp32-float8 -> f16x8
#define XFRAG(DST, PTR)                                      \
  do {                                                       \
    float4 a_ = *(const float4*)(PTR);                       \
    float4 b_ = *(const float4*)((PTR) + 4);                 \
    f16x8 h_;                                                \
    h_[0] = (f16)a_.x; h_[1] = (f16)a_.y; h_[2] = (f16)a_.z; \
    h_[3] = (f16)a_.w; h_[4] = (f16)b_.x; h_[5] = (f16)b_.y; \
    h_[6] = (f16)b_.z; h_[7] = (f16)b_.w;                    \
    DST = h_;                                                \
  } while (0)

// ---------------- prep (unchanged from R9 — verified) ----------------
// Wt layout (8 MB):  byte = ((ncg*64 + d)*16 + ic)*1024 + hf*512 + c*16 + j*2
//   <- W1[d][ic*16 + hf*8 + j][ncg*32 + c]   (B-frag lane-linear, 1KB chunks)
// Xt layout (2 MB):  byte = ((t64*16 + ic)*2 + hf)*1024 + row*16 + j*2
//   <- x[t64*64 + row][ic*16 + hf*8 + j]     (A-frag lane-linear, 64-row tiles)
// Bt layout (32 KB): byte = ((ncg*4 + kc)*2 + hf)*512 + c*16 + j*2
//   <- b1[kc*16 + hf*8 + j][ncg*32 + c]
__global__ __launch_bounds__(256) void prep(const float* __restrict__ W,
                                            const float* __restrict__ B1,
                                            const float* __restrict__ X,
                                            f16* __restrict__ Wt,
                                            f16* __restrict__ Xt,
                                            f16* __restrict__ Bt) {
  const int b = blockIdx.x, t = threadIdx.x;
  if (b < 512) {
    const int d = b >> 3, grp = b & 7;
#pragma unroll
    for (int r = 0; r < 4; ++r) {
      const int u = (r << 8) + t;
      const int ibq = u >> 8;
      const int o = u & 255;
      const int ib = (grp << 2) + ibq;  // i = ib*8 + j
      f16x8 h;
#pragma unroll
      for (int j = 0; j < 8; ++j)
        h[j] = (f16)W[((size_t)d * 256 + (ib << 3) + j) * 256 + o];
      const int ncg = o >> 5, c = o & 31, ic = ib >> 1, hb = ib & 1;
      *(f16x8*)((char*)Wt + ((((size_t)ncg * 64 + d) * 16 + ic) << 10) +
                (hb << 9) + (c << 4)) = h;
    }
  } else if (b < 576) {
    const int mb = b - 512;  // 64-row tiles
#pragma unroll
    for (int rep = 0; rep < 8; ++rep) {
      const int u = (rep << 8) + t;
      const int row = u & 63, ish = u >> 6;  // i = ish*8 + j
      const float* src = X + ((size_t)((mb << 6) + row)) * 256 + (ish << 3);
      f16x8 h;
      XFRAG(h, src);
      *(f16x8*)((char*)Xt + ((((size_t)mb * 16 + (ish >> 1)) * 2 + (ish & 1)) << 10) +
                (row << 4)) = h;
    }
  } else {
#pragma unroll
    for (int kb = 0; kb < 8; ++kb) {  // k = kb*8 + j
      const float* src = B1 + ((size_t)kb << 3) * 256 + t;
      f16x8 h;
#pragma unroll
      for (int j = 0; j < 8; ++j) h[j] = (f16)src[(size_t)j << 8];
      *(f16x8*)((char*)Bt + (((size_t)(t >> 5) * 4 + (kb >> 1)) << 10) +
                ((kb & 1) << 9) + ((t & 31) << 4)) = h;
    }
  }
}

// ---- main: 512 blocks = 32 mb (128 rows) x 8 nc (32 cols) x 2 ksi (8 ics) --
__global__ __launch_bounds__(512, 4) void mlp_main(const float* __restrict__ Q,
                                                   const f16* __restrict__ Wt,
                                                   const f16* __restrict__ Xt,
                                                   const f16* __restrict__ Bt,
                                                   float* __restrict__ P) {
  __shared__ __align__(16) char smem[73728];  // sx (32 KB) ∪ red[4][128][36]

  const int bid = blockIdx.x;
  const int nc = bid & 7;          // XCD-affine column tile
  const int ksi = (bid >> 3) & 1;  // ic-half
  const int mb = bid >> 4;         // 0..31, 128-row tile
  const int t = threadIdx.x;
  const int w = t >> 6;            // 0..7, d-range [w*8, w*8+8)
  const int l = t & 63;
  const int l31 = l & 31;
  const int hf = l >> 5;
  const int rot = mb & 7;          // d-walk stagger

  // W base: chunk(nc, d = w*8 + ddAbs, icAbs = ksi*8 + ic) at
  //   (nc<<20) + ((w*8+ddAbs)<<14) + (icAbs<<10); lane adds l*16.
  const char* wB = (const char*)Wt + ((size_t)nc << 20) + (w << 17) +
                   (ksi << 13) + (l << 4);
#define WADDR(S) \
  (wB + ((((((S) & 7) + rot) & 7)) << 14) + ((((S) >> 3)) << 10))

  // ---- prologue ----
  // q scalars, rotated: qv[mt][dt] = q[mb*128 + mt*32 + l31][w*8 + (dt+rot)&7]
  f16x8 qv[4];
#pragma unroll
  for (int mt = 0; mt < 4; ++mt) {
    const float* qp = Q + ((size_t)((mb << 7) + (mt << 5) + l31)) * QDIM + (w << 3);
#pragma unroll
    for (int dt = 0; dt < 8; ++dt) qv[mt][dt] = (f16)qp[(dt + rot) & 7];
  }

  // W ring prologue: steps 0..3
  f16x8 Wr0 = *(const f16x8*)WADDR(0);
  f16x8 Wr1 = *(const f16x8*)WADDR(1);
  f16x8 Wr2 = *(const f16x8*)WADDR(2);
  f16x8 Wr3 = *(const f16x8*)WADDR(3);

  // x staging: wave w stages ic=w (4 slabs of 1 KB)
#pragma unroll
  for (int r = 0; r < 4; ++r) {
    const int t64 = (r >> 1) & 1, half = r & 1;
    const char* src = (const char*)Xt +
        ((((size_t)((mb << 1) + t64) << 4) + (ksi << 3) + w) << 11) +
        (half << 10) + (l << 4);
    gl_lds16(src, smem + ((((w << 2) + r)) << 10) + (l << 4));
  }

  f32x16 acc0, acc1, acc2, acc3;
#pragma unroll
  for (int r = 0; r < 16; ++r) { acc0[r] = 0.f; acc1[r] = 0.f;
                                 acc2[r] = 0.f; acc3[r] = 0.f; }

  __syncthreads();  // x staged (drains vmcnt) — ONLY barrier before reduce

  f16x8 xf0, xf1, xf2, xf3;
#define LOADXF(IC)                                                          \
  do {                                                                      \
    const char* xb_ = smem + ((IC) << 12) + (hf << 10) + (l31 << 4);        \
    xf0 = *(const f16x8*)(xb_);                                             \
    xf1 = *(const f16x8*)(xb_ + 512);                                       \
    xf2 = *(const f16x8*)(xb_ + 2048);                                      \
    xf3 = *(const f16x8*)(xb_ + 2560);                                      \
  } while (0)
  // sx chunk (ic, t64=mt>>1) at ((ic*2+t64)<<11); + (mt&1)<<9 within.

#define STEP(S, WR)                                                         \
  do {                                                                      \
    f16x8 wf_ = WR;                                                         \
    if ((S) < 60) WR = *(const f16x8*)WADDR((S) + 4);                       \
    acc0 = __builtin_amdgcn_mfma_f32_32x32x16_f16(xf0 * qv[0][(S) & 7],     \
                                                  wf_, acc0, 0, 0, 0);      \
    acc1 = __builtin_amdgcn_mfma_f32_32x32x16_f16(xf1 * qv[1][(S) & 7],     \
                                                  wf_, acc1, 0, 0, 0);      \
    acc2 = __builtin_amdgcn_mfma_f32_32x32x16_f16(xf2 * qv[2][(S) & 7],     \
                                                  wf_, acc2, 0, 0, 0);      \
    acc3 = __builtin_amdgcn_mfma_f32_32x32x16_f16(xf3 * qv[3][(S) & 7],     \
                                                  wf_, acc3, 0, 0, 0);      \
  } while (0)

#pragma unroll
  for (int ic = 0; ic < 8; ++ic) {
    LOADXF(ic);
    STEP(ic * 8 + 0, Wr0);
    STEP(ic * 8 + 1, Wr1);
    STEP(ic * 8 + 2, Wr2);
    STEP(ic * 8 + 3, Wr3);
    STEP(ic * 8 + 4, Wr0);
    STEP(ic * 8 + 5, Wr1);
    STEP(ic * 8 + 6, Wr2);
    STEP(ic * 8 + 7, Wr3);
  }

  // bias (ksi==0, wave 7): 4 chunks over QDIM, A = q-frag, B = Bt
  if (ksi == 0 && w == 7) {
#pragma unroll
    for (int kc = 0; kc < 4; ++kc) {
      f16x8 bf = *(const f16x8*)((const char*)Bt +
          (((size_t)nc * 4 + kc) << 10) + (hf << 9) + (l31 << 4));
      f16x8 q0, q1, q2, q3;
      XFRAG(q0, Q + ((size_t)((mb << 7) + l31)) * QDIM + (kc << 4) + (hf << 3));
      XFRAG(q1, Q + ((size_t)((mb << 7) + 32 + l31)) * QDIM + (kc << 4) + (hf << 3));
      XFRAG(q2, Q + ((size_t)((mb << 7) + 64 + l31)) * QDIM + (kc << 4) + (hf << 3));
      XFRAG(q3, Q + ((size_t)((mb << 7) + 96 + l31)) * QDIM + (kc << 4) + (hf << 3));
      acc0 = __builtin_amdgcn_mfma_f32_32x32x16_f16(q0, bf, acc0, 0, 0, 0);
      acc1 = __builtin_amdgcn_mfma_f32_32x32x16_f16(q1, bf, acc1, 0, 0, 0);
      acc2 = __builtin_amdgcn_mfma_f32_32x32x16_f16(q2, bf, acc2, 0, 0, 0);
      acc3 = __builtin_amdgcn_mfma_f32_32x32x16_f16(q3, bf, acc3, 0, 0, 0);
    }
  }

  // ---- two-phase 8-way d-reduction in LDS (smem reused; x is dead) ----
  // C/D (32x32): col = lane&31, row = (reg&3) + 8*(reg>>2) + 4*(lane>>5)
#define RED(WQ, ROW, COL) \
  (((float*)smem)[(((WQ) * 128 + (ROW)) * 36) + (COL)])
  __syncthreads();  // all sx reads done before overwrite
  if (w < 4) {
#pragma unroll
    for (int r = 0; r < 16; ++r) {
      const int rr = (r & 3) + ((r >> 2) << 3) + (hf << 2);
      RED(w, rr, l31) = acc0[r];
      RED(w, 32 + rr, l31) = acc1[r];
      RED(w, 64 + rr, l31) = acc2[r];
      RED(w, 96 + rr, l31) = acc3[r];
    }
  }
  __syncthreads();
  if (w >= 4) {
#pragma unroll
    for (int r = 0; r < 16; ++r) {
      const int rr = (r & 3) + ((r >> 2) << 3) + (hf << 2);
      RED(w - 4, rr, l31) += acc0[r];
      RED(w - 4, 32 + rr, l31) += acc1[r];
      RED(w - 4, 64 + rr, l31) += acc2[r];
      RED(w - 4, 96 + rr, l31) += acc3[r];
    }
  }
  __syncthreads();

  // final: 512 threads x 8 cols; sum 4 regions; store to stripe ksi
  const int row = t >> 2;
  const int c0 = (t & 3) << 3;
  float s[8];
#pragma unroll
  for (int j = 0; j < 8; ++j) s[j] = 0.f;
#pragma unroll
  for (int j = 0; j < 4; ++j) {
    const float* rp = &RED(j, row, c0);
    float4 v0 = *(const float4*)rp;
    float4 v1 = *(const float4*)(rp + 4);
    s[0] += v0.x; s[1] += v0.y; s[2] += v0.z; s[3] += v0.w;
    s[4] += v1.x; s[5] += v1.y; s[6] += v1.z; s[7] += v1.w;
  }
  float4 o0 = {s[0], s[1], s[2], s[3]};
  float4 o1 = {s[4], s[5], s[6], s[7]};
  float* op = P + ((size_t)ksi << 20) +
              ((size_t)((mb << 7) + row)) * 256 + (nc << 5) + c0;
  *(float4*)op = o0;
  *(float4*)(op + 4) = o1;
}

// out = P[0] + P[1]. 1024 blocks x 256 threads x float4.
__global__ __launch_bounds__(256) void reduce2(const float* __restrict__ P,
                                               float* __restrict__ out) {
  const size_t i = (((size_t)blockIdx.x << 8) + threadIdx.x) << 2;
  float4 a = *(const float4*)(P + i);
  float4 b = *(const float4*)(P + ((size_t)1 << 20) + i);
  a.x += b.x; a.y += b.y; a.z += b.z; a.w += b.w;
  *(float4*)(out + i) = a;
}

extern "C" void kernel_launch(void* const* d_in, const int* in_sizes, int n_in,
                              void* d_out, int out_size, void* d_ws, size_t ws_size,
                              hipStream_t stream) {
  (void)in_sizes; (void)n_in; (void)out_size; (void)ws_size;
  const float* x  = (const float*)d_in[0];   // [4096,256]
  const float* q  = (const float*)d_in[1];   // [4096,64]
  const float* W1 = (const float*)d_in[2];   // [64,256,256]
  const float* b1 = (const float*)d_in[3];   // [64,256]
  float* out = (float*)d_out;                // [4096,256] fp32

  // ws: Wt 8 MB | Bt 32 KB | Xt 2 MB | P 2 x 4 MB  (~18 MB)
  f16* Wt = (f16*)d_ws;
  f16* Bt = (f16*)((char*)d_ws + ((size_t)8 << 20));
  f16* Xt = (f16*)((char*)d_ws + ((size_t)8 << 20) + 32768);
  float* P = (float*)((char*)d_ws + ((size_t)8 << 20) + 32768 + ((size_t)2 << 20));

  prep<<<577, 256, 0, stream>>>(W1, b1, x, Wt, Xt, Bt);
  mlp_main<<<512, 512, 0, stream>>>(q, Wt, Xt, Bt, P);
  reduce2<<<1024, 256, 0, stream>>>(P, out);
}